// Round 1
// baseline (1309.713 us; speedup 1.0000x reference)
//
#include <hip/hip_runtime.h>
#include <hip/hip_fp16.h>

#define N_NODES 100000
#define N_EDGES 3200000
#define NBUCKETS 391          // ceil(100000 / 256); bucket = dst >> 8
#define NCHUNKB 256           // blocks for hist/scatter
#define CHUNK 12500           // N_EDGES / NCHUNKB
// FEATURE == HIDDEN == 128
// edge_index arrives as int32: ei[0..E) = src, ei[E..2E) = dst.

typedef __attribute__((ext_vector_type(8))) short sh8;   // 8 bf16 (4 VGPRs)
typedef __attribute__((ext_vector_type(4))) float fl4;   // MFMA acc
typedef __attribute__((ext_vector_type(2))) float f2v;   // for nontemporal float2 store

// split fp32 into bf16 hi + bf16 lo (both round-to-nearest-even)
__device__ inline void split_bf16(float x, short& hi, short& lo) {
    unsigned u = __float_as_uint(x);
    unsigned r = u + 0x7FFFu + ((u >> 16) & 1u);
    hi = (short)(r >> 16);
    float hif = __uint_as_float(r & 0xFFFF0000u);
    float lof = x - hif;
    unsigned u2 = __float_as_uint(lof);
    lo = (short)((u2 + 0x7FFFu + ((u2 >> 16) & 1u)) >> 16);
}

// ---------------- bucketed CSR build ----------------

__global__ __launch_bounds__(256) void k_bhist(const int* __restrict__ ei_dst,
                                               int* __restrict__ bucket_cnt) {
    __shared__ int h[NBUCKETS];
    int t = threadIdx.x;
    for (int i = t; i < NBUCKETS; i += 256) h[i] = 0;
    __syncthreads();
    int base = blockIdx.x * CHUNK;
    for (int i = t; i < CHUNK; i += 256)
        atomicAdd(&h[ei_dst[base + i] >> 8], 1);
    __syncthreads();
    for (int i = t; i < NBUCKETS; i += 256)
        if (h[i]) atomicAdd(&bucket_cnt[i], h[i]);
}

__global__ __launch_bounds__(512) void k_bscan(const int* __restrict__ bucket_cnt,
                                               int* __restrict__ bucket_base,
                                               int* __restrict__ bucket_fill) {
    __shared__ int s[512];
    int t = threadIdx.x;
    int v = (t < NBUCKETS) ? bucket_cnt[t] : 0;
    s[t] = v;
    __syncthreads();
    for (int off = 1; off < 512; off <<= 1) {
        int x = (t >= off) ? s[t - off] : 0;
        __syncthreads();
        s[t] += x;
        __syncthreads();
    }
    int ex = s[t] - v;
    if (t < NBUCKETS) { bucket_base[t] = ex; bucket_fill[t] = ex; }
    if (t == NBUCKETS - 1) bucket_base[NBUCKETS] = s[t];
}

// packed entry: src (17 bits) | dstlocal (8 bits) << 17
__global__ __launch_bounds__(256) void k_bscatter(const int* __restrict__ ei,
                                                  int* __restrict__ bucket_fill,
                                                  unsigned* __restrict__ bpairs) {
    __shared__ int h[NBUCKETS];
    __shared__ int basep[NBUCKETS];
    int t = threadIdx.x;
    const int* dstp = ei + N_EDGES;
    int base = blockIdx.x * CHUNK;

    for (int i = t; i < NBUCKETS; i += 256) h[i] = 0;
    __syncthreads();
    for (int i = t; i < CHUNK; i += 256)
        atomicAdd(&h[dstp[base + i] >> 8], 1);
    __syncthreads();
    for (int i = t; i < NBUCKETS; i += 256) {
        int c = h[i];
        basep[i] = c ? atomicAdd(&bucket_fill[i], c) : 0;
    }
    __syncthreads();
    for (int i = t; i < NBUCKETS; i += 256) h[i] = 0;  // reuse as rank
    __syncthreads();
    for (int i = t; i < CHUNK; i += 256) {
        int d = dstp[base + i];
        int s = ei[base + i];
        int b = d >> 8;
        int r = atomicAdd(&h[b], 1);
        bpairs[basep[b] + r] = (unsigned)s | ((unsigned)(d & 255) << 17);
    }
}

__global__ __launch_bounds__(256) void k_bbuild(const unsigned* __restrict__ bpairs,
                                                const int* __restrict__ bucket_base,
                                                int* __restrict__ row_ptr,
                                                int* __restrict__ cnt,
                                                float* __restrict__ dinv,
                                                int* __restrict__ csr_src) {
    __shared__ int h[256];
    __shared__ int sc[256];
    int b = blockIdx.x;
    int t = threadIdx.x;
    int e0 = bucket_base[b], e1 = bucket_base[b + 1];

    h[t] = 0;
    __syncthreads();
    for (int i = e0 + t; i < e1; i += 256)
        atomicAdd(&h[bpairs[i] >> 17], 1);
    __syncthreads();
    int v = h[t];
    sc[t] = v;
    __syncthreads();
    for (int off = 1; off < 256; off <<= 1) {
        int x = (t >= off) ? sc[t - off] : 0;
        __syncthreads();
        sc[t] += x;
        __syncthreads();
    }
    int ex = sc[t] - v;
    int node = b * 256 + t;
    if (node < N_NODES) {
        cnt[node] = v;
        dinv[node] = rsqrtf((float)(v + 1));
        row_ptr[node] = e0 + ex;
    }
    __syncthreads();
    h[t] = e0 + ex;               // absolute fill cursor
    __syncthreads();
    for (int i = e0 + t; i < e1; i += 256) {
        unsigned p = bpairs[i];
        int pos = atomicAdd(&h[p >> 17], 1);
        csr_src[pos] = (int)(p & 0x1FFFFu);
    }
}

// ------- W repack (+ fused bucket_cnt zero in the extra block) -------
// B-frag (16x16x32): lane = q*16 + n16 holds B[k = ks*32 + q*8 + j][n = c*16 + n16],
// j = 0..7 contiguous. Storage: frag[((l*32 + ks*8 + c)*64 + lane)*8 + j].

__global__ __launch_bounds__(256) void k_wprep(const float* __restrict__ W0,
                                               const float* __restrict__ W1,
                                               const float* __restrict__ W2,
                                               short* __restrict__ fhi,
                                               short* __restrict__ flo,
                                               int* __restrict__ bucket_cnt) {
    if (blockIdx.x == 192) {   // fused: zero the bucket counters
        for (int i = threadIdx.x; i < NBUCKETS; i += 256) bucket_cnt[i] = 0;
        return;
    }
    int idx = blockIdx.x * 256 + threadIdx.x;   // 3 * 16384
    int l = idx >> 14, e = idx & 16383;
    const float* W = (l == 0) ? W0 : (l == 1) ? W1 : W2;
    float w = W[e];
    int k = e >> 7, n = e & 127;
    int ks = k >> 5, q = (k >> 3) & 3, j = k & 7;
    int c = n >> 4, n16 = n & 15;
    int lane = q * 16 + n16;
    int dst = ((l * 32 + ks * 8 + c) * 64 + lane) * 8 + j;
    short hi, lo;
    split_bf16(w, hi, lo);
    fhi[dst] = hi;
    flo[dst] = lo;
}

// ------- GEMM v5: H16 = fp16( (X @ W) * dinv[row] ), sliced output layout -------
// H16 is stored FEATURE-SLICED: H16[(slice*N_NODES + row)*16 + n16], slice = feature>>4.
// A-input: standard [row][128] for layer 0 (sliced=0), sliced fp32 for layers 1-2.
// 512 threads = 8 waves, 16 rows/wave -> 128 rows/block; split-bf16 MFMA (3 per acc).

__global__ __launch_bounds__(512, 4) void k_gemm_mfma(const float* __restrict__ X,
                                                      const short* __restrict__ fhi,
                                                      const short* __restrict__ flo,
                                                      const float* __restrict__ dinv,
                                                      __half* __restrict__ H16,
                                                      int sliced) {
    __shared__ short Bh[16384];    // 32 KB
    __shared__ short Bl[16384];    // 32 KB

    int t = threadIdx.x;
    int wave = t >> 6, lane = t & 63;
    int q = lane >> 4, n16 = lane & 15;
    int row_base = blockIdx.x * 128 + wave * 16;

    // hoist all A loads: 4 ks x 32 B per lane (in flight before any use)
    int r0 = row_base + n16;
    if (r0 > N_NODES - 1) r0 = N_NODES - 1;
    float4 a[4][2];
    if (!sliced) {
        const float* p0 = X + (long long)r0 * 128 + q * 8;
#pragma unroll
        for (int ks = 0; ks < 4; ++ks) {
            a[ks][0] = *(const float4*)(p0 + ks * 32);
            a[ks][1] = *(const float4*)(p0 + ks * 32 + 4);
        }
    } else {
        // feature chunk f0 = q*8 + ks*32 lives at slice f0>>4, offset f0&15
#pragma unroll
        for (int ks = 0; ks < 4; ++ks) {
            int sl = ks * 2 + (q >> 1);
            const float* p = X + ((long long)sl * N_NODES + r0) * 16 + (q & 1) * 8;
            a[ks][0] = *(const float4*)p;
            a[ks][1] = *(const float4*)(p + 4);
        }
    }

    // stage B frags into LDS: 2048 float4 per array, 512 threads -> 4 iters
    {
        const float4* sh_ = (const float4*)fhi;
        const float4* sl_ = (const float4*)flo;
        float4* dh = (float4*)Bh;
        float4* dl = (float4*)Bl;
#pragma unroll
        for (int i = 0; i < 4; ++i) {
            dh[t + i * 512] = sh_[t + i * 512];
            dl[t + i * 512] = sl_[t + i * 512];
        }
    }

    // split A into bf16 hi/lo fragments (under vmcnt shadow)
    sh8 ah[4], al[4];
#pragma unroll
    for (int ks = 0; ks < 4; ++ks) {
        float xs[8];
        xs[0] = a[ks][0].x; xs[1] = a[ks][0].y; xs[2] = a[ks][0].z; xs[3] = a[ks][0].w;
        xs[4] = a[ks][1].x; xs[5] = a[ks][1].y; xs[6] = a[ks][1].z; xs[7] = a[ks][1].w;
#pragma unroll
        for (int j = 0; j < 8; ++j) {
            short h, l;
            split_bf16(xs[j], h, l);
            ah[ks][j] = h;
            al[ks][j] = l;
        }
    }

    fl4 acc[8];
#pragma unroll
    for (int c = 0; c < 8; ++c) acc[c] = (fl4){0.f, 0.f, 0.f, 0.f};

    __syncthreads();

    // MFMA loop: pure LDS reads + MFMA (compiler pipelines via lgkmcnt)
#pragma unroll
    for (int ks = 0; ks < 4; ++ks)
#pragma unroll
        for (int c = 0; c < 8; ++c) {
            sh8 bh = *(const sh8*)&Bh[((ks * 8 + c) * 64 + lane) * 8];
            sh8 bl = *(const sh8*)&Bl[((ks * 8 + c) * 64 + lane) * 8];
            acc[c] = __builtin_amdgcn_mfma_f32_16x16x32_bf16(ah[ks], bh, acc[c], 0, 0, 0);
            acc[c] = __builtin_amdgcn_mfma_f32_16x16x32_bf16(al[ks], bh, acc[c], 0, 0, 0);
            acc[c] = __builtin_amdgcn_mfma_f32_16x16x32_bf16(ah[ks], bl, acc[c], 0, 0, 0);
        }

    // epilogue: C/D layout row = q*4 + reg, col = c*16 + n16 -> sliced H16
#pragma unroll
    for (int reg = 0; reg < 4; ++reg) {
        int grow = row_base + q * 4 + reg;
        if (grow < N_NODES) {
            float sc = dinv[grow];
#pragma unroll
            for (int c = 0; c < 8; ++c)
                H16[(c * N_NODES + grow) * 16 + n16] = __float2half(acc[c][reg] * sc);
        }
    }
}

// ---------------- gather aggregation + bias + relu (feature-sliced) ----------------
// blockIdx % 8 = feature slice (pins slice to one XCD via round-robin dispatch);
// each XCD's 4 MB L2 holds its 3.2 MB H16 slice -> random src reads become L2 hits.
// Per wave: 1 node, 8 lanes/edge (4 B half2 each), 8 edges per load instruction.
// csr_src + outputs use nontemporal ops so streams don't evict the pinned slice.

__global__ __launch_bounds__(256) void k_gather(const __half2* __restrict__ H2,
                                                const int* __restrict__ csr_src,
                                                const int* __restrict__ row_ptr,
                                                const int* __restrict__ cnt,
                                                const float* __restrict__ dinv,
                                                const float* __restrict__ b,
                                                float* __restrict__ out,
                                                int std_out) {
    int s = blockIdx.x & 7;                  // slice -> XCD (round-robin heuristic)
    int grp = blockIdx.x >> 3;               // node group: 16 nodes per block
    int wv = __builtin_amdgcn_readfirstlane(threadIdx.x >> 6);
    int lane = threadIdx.x & 63;
    int g8 = lane >> 3, f4 = lane & 7;       // edge subgroup / feature-pair
    int sbase = s * N_NODES;
    float2 bb = ((const float2*)b)[s * 8 + f4];

    for (int k = 0; k < 4; ++k) {            // 4 nodes per wave
        int node = grp * 16 + wv * 4 + k;
        int start = row_ptr[node];
        int n = cnt[node];

        float2 self_ = __half22float2(H2[(sbase + node) * 8 + f4]);
        float accx = (g8 == 0) ? self_.x : 0.0f;
        float accy = (g8 == 0) ? self_.y : 0.0f;

        for (int j = 0; j < n; j += 32) {
            int idx[4];
#pragma unroll
            for (int u = 0; u < 4; ++u) {
                int e = j + u * 8 + g8;
                idx[u] = (e < n) ? __builtin_nontemporal_load(csr_src + start + e) : -1;
            }
#pragma unroll
            for (int u = 0; u < 4; ++u)
                if (idx[u] >= 0) {
                    float2 h = __half22float2(H2[(sbase + idx[u]) * 8 + f4]);
                    accx += h.x; accy += h.y;
                }
        }

        // reduce across the 8 edge subgroups (lanes l, l^8, l^16, ..., l^56)
#pragma unroll
        for (int m = 8; m <= 32; m <<= 1) {
            accx += __shfl_xor(accx, m, 64);
            accy += __shfl_xor(accy, m, 64);
        }

        if (g8 == 0) {
            float dd = dinv[node];
            f2v v;
            v.x = fmaxf(fmaf(accx, dd, bb.x), 0.0f);
            v.y = fmaxf(fmaf(accy, dd, bb.y), 0.0f);
            if (std_out)
                __builtin_nontemporal_store(v, (f2v*)(out + node * 128 + s * 16) + f4);
            else
                __builtin_nontemporal_store(v, (f2v*)(out + (sbase + node) * 16) + f4);
        }
    }
}

// ---------------- launch ----------------

extern "C" void kernel_launch(void* const* d_in, const int* in_sizes, int n_in,
                              void* d_out, int out_size, void* d_ws, size_t ws_size,
                              hipStream_t stream) {
    const float* x  = (const float*)d_in[0];
    const int*   ei = (const int*)d_in[1];   // int32: [0,E)=src, [E,2E)=dst
    const float* Wm[3] = {(const float*)d_in[2], (const float*)d_in[4], (const float*)d_in[6]};
    const float* bv[3] = {(const float*)d_in[3], (const float*)d_in[5], (const float*)d_in[7]};
    float* out = (float*)d_out;

    char* w = (char*)d_ws;
    int*      row_ptr     = (int*)(w + 0);            // 0.4 MB
    int*      cnt         = (int*)(w + 400384);       // 0.4 MB
    float*    dinv        = (float*)(w + 800768);     // 0.4 MB
    int*      bucket_cnt  = (int*)(w + 1201152);      // 2 KB
    int*      bucket_base = (int*)(w + 1203200);      // 2 KB
    int*      bucket_fill = (int*)(w + 1205248);      // 2 KB
    unsigned* bpairs      = (unsigned*)(w + 1207296); // 12.8 MB
    int*      csr_src     = (int*)(w + 14007808);     // 12.8 MB
    short*    fragHi      = (short*)(w + 26808320);   // 96 KB (3 layers)
    short*    fragLo      = (short*)(w + 26906624);   // 96 KB
    __half*   H16         = (__half*)(w + 27004928);  // 25.6 MB sliced (total ~52.6 MB)

    // W repack (+ fused bucket zero), then bucketed counting-sort CSR build
    k_wprep<<<193, 256, 0, stream>>>(Wm[0], Wm[1], Wm[2], fragHi, fragLo, bucket_cnt);
    k_bhist<<<NCHUNKB, 256, 0, stream>>>(ei + N_EDGES, bucket_cnt);
    k_bscan<<<1, 512, 0, stream>>>(bucket_cnt, bucket_base, bucket_fill);
    k_bscatter<<<NCHUNKB, 256, 0, stream>>>(ei, bucket_fill, bpairs);
    k_bbuild<<<NBUCKETS, 256, 0, stream>>>(bpairs, bucket_base, row_ptr, cnt, dinv, csr_src);

    // 3 GCN layers; d_out doubles as the (sliced) fp32 ping buffer
    const float* xin = x;
    for (int l = 0; l < 3; ++l) {
        k_gemm_mfma<<<(N_NODES + 127) / 128, 512, 0, stream>>>(xin, fragHi + l * 16384,
                                                               fragLo + l * 16384, dinv, H16,
                                                               l > 0);
        k_gather<<<8 * (N_NODES / 16), 256, 0, stream>>>((const __half2*)H16, csr_src,
                                                         row_ptr, cnt, dinv, bv[l], out,
                                                         l == 2);
        xin = out;
    }
}

// Round 2
// 1021.479 us; speedup vs baseline: 1.2822x; 1.2822x over previous
//
#include <hip/hip_runtime.h>
#include <hip/hip_fp16.h>

#define N_NODES 100000
#define N_EDGES 3200000
#define NBUCKETS 391          // ceil(100000 / 256); bucket = dst >> 8
#define NCHUNKB 256           // blocks for hist/scatter
#define CHUNK 12500           // N_EDGES / NCHUNKB
#define GNODES 32             // nodes per gather block
#define GCAP 8192             // LDS-staged edges per gather block (32 KB)
// FEATURE == HIDDEN == 128
// edge_index arrives as int32: ei[0..E) = src, ei[E..2E) = dst.

typedef __attribute__((ext_vector_type(8))) short sh8;   // 8 bf16 (4 VGPRs)
typedef __attribute__((ext_vector_type(4))) float fl4;   // MFMA acc
typedef __attribute__((ext_vector_type(2))) float f2v;   // for nontemporal float2 store

// split fp32 into bf16 hi + bf16 lo (both round-to-nearest-even)
__device__ inline void split_bf16(float x, short& hi, short& lo) {
    unsigned u = __float_as_uint(x);
    unsigned r = u + 0x7FFFu + ((u >> 16) & 1u);
    hi = (short)(r >> 16);
    float hif = __uint_as_float(r & 0xFFFF0000u);
    float lof = x - hif;
    unsigned u2 = __float_as_uint(lof);
    lo = (short)((u2 + 0x7FFFu + ((u2 >> 16) & 1u)) >> 16);
}

// ---------------- bucketed CSR build ----------------

__global__ __launch_bounds__(256) void k_bhist(const int* __restrict__ ei_dst,
                                               int* __restrict__ bucket_cnt) {
    __shared__ int h[NBUCKETS];
    int t = threadIdx.x;
    for (int i = t; i < NBUCKETS; i += 256) h[i] = 0;
    __syncthreads();
    int base = blockIdx.x * CHUNK;
    for (int i = t; i < CHUNK; i += 256)
        atomicAdd(&h[ei_dst[base + i] >> 8], 1);
    __syncthreads();
    for (int i = t; i < NBUCKETS; i += 256)
        if (h[i]) atomicAdd(&bucket_cnt[i], h[i]);
}

__global__ __launch_bounds__(512) void k_bscan(const int* __restrict__ bucket_cnt,
                                               int* __restrict__ bucket_base,
                                               int* __restrict__ bucket_fill) {
    __shared__ int s[512];
    int t = threadIdx.x;
    int v = (t < NBUCKETS) ? bucket_cnt[t] : 0;
    s[t] = v;
    __syncthreads();
    for (int off = 1; off < 512; off <<= 1) {
        int x = (t >= off) ? s[t - off] : 0;
        __syncthreads();
        s[t] += x;
        __syncthreads();
    }
    int ex = s[t] - v;
    if (t < NBUCKETS) { bucket_base[t] = ex; bucket_fill[t] = ex; }
    if (t == NBUCKETS - 1) bucket_base[NBUCKETS] = s[t];
}

// packed entry: src (17 bits) | dstlocal (8 bits) << 17
__global__ __launch_bounds__(256) void k_bscatter(const int* __restrict__ ei,
                                                  int* __restrict__ bucket_fill,
                                                  unsigned* __restrict__ bpairs) {
    __shared__ int h[NBUCKETS];
    __shared__ int basep[NBUCKETS];
    int t = threadIdx.x;
    const int* dstp = ei + N_EDGES;
    int base = blockIdx.x * CHUNK;

    for (int i = t; i < NBUCKETS; i += 256) h[i] = 0;
    __syncthreads();
    for (int i = t; i < CHUNK; i += 256)
        atomicAdd(&h[dstp[base + i] >> 8], 1);
    __syncthreads();
    for (int i = t; i < NBUCKETS; i += 256) {
        int c = h[i];
        basep[i] = c ? atomicAdd(&bucket_fill[i], c) : 0;
    }
    __syncthreads();
    for (int i = t; i < NBUCKETS; i += 256) h[i] = 0;  // reuse as rank
    __syncthreads();
    for (int i = t; i < CHUNK; i += 256) {
        int d = dstp[base + i];
        int s = ei[base + i];
        int b = d >> 8;
        int r = atomicAdd(&h[b], 1);
        bpairs[basep[b] + r] = (unsigned)s | ((unsigned)(d & 255) << 17);
    }
}

__global__ __launch_bounds__(256) void k_bbuild(const unsigned* __restrict__ bpairs,
                                                const int* __restrict__ bucket_base,
                                                int* __restrict__ row_ptr,
                                                int* __restrict__ cnt,
                                                float* __restrict__ dinv,
                                                int* __restrict__ csr_src) {
    __shared__ int h[256];
    __shared__ int sc[256];
    int b = blockIdx.x;
    int t = threadIdx.x;
    int e0 = bucket_base[b], e1 = bucket_base[b + 1];

    h[t] = 0;
    __syncthreads();
    for (int i = e0 + t; i < e1; i += 256)
        atomicAdd(&h[bpairs[i] >> 17], 1);
    __syncthreads();
    int v = h[t];
    sc[t] = v;
    __syncthreads();
    for (int off = 1; off < 256; off <<= 1) {
        int x = (t >= off) ? sc[t - off] : 0;
        __syncthreads();
        sc[t] += x;
        __syncthreads();
    }
    int ex = sc[t] - v;
    int node = b * 256 + t;
    if (node < N_NODES) {
        cnt[node] = v;
        dinv[node] = rsqrtf((float)(v + 1));
        row_ptr[node] = e0 + ex;
    }
    __syncthreads();
    h[t] = e0 + ex;               // absolute fill cursor
    __syncthreads();
    for (int i = e0 + t; i < e1; i += 256) {
        unsigned p = bpairs[i];
        int pos = atomicAdd(&h[p >> 17], 1);
        csr_src[pos] = (int)(p & 0x1FFFFu);
    }
}

// ------- W repack (+ fused bucket_cnt zero in the extra block) -------
// B-frag (16x16x32): lane = q*16 + n16 holds B[k = ks*32 + q*8 + j][n = c*16 + n16],
// j = 0..7 contiguous. Storage: frag[((l*32 + ks*8 + c)*64 + lane)*8 + j].

__global__ __launch_bounds__(256) void k_wprep(const float* __restrict__ W0,
                                               const float* __restrict__ W1,
                                               const float* __restrict__ W2,
                                               short* __restrict__ fhi,
                                               short* __restrict__ flo,
                                               int* __restrict__ bucket_cnt) {
    if (blockIdx.x == 192) {   // fused: zero the bucket counters
        for (int i = threadIdx.x; i < NBUCKETS; i += 256) bucket_cnt[i] = 0;
        return;
    }
    int idx = blockIdx.x * 256 + threadIdx.x;   // 3 * 16384
    int l = idx >> 14, e = idx & 16383;
    const float* W = (l == 0) ? W0 : (l == 1) ? W1 : W2;
    float w = W[e];
    int k = e >> 7, n = e & 127;
    int ks = k >> 5, q = (k >> 3) & 3, j = k & 7;
    int c = n >> 4, n16 = n & 15;
    int lane = q * 16 + n16;
    int dst = ((l * 32 + ks * 8 + c) * 64 + lane) * 8 + j;
    short hi, lo;
    split_bf16(w, hi, lo);
    fhi[dst] = hi;
    flo[dst] = lo;
}

// ------- GEMM v5: H16 = fp16( (X @ W) * dinv[row] ), sliced output layout -------
// H16 is stored FEATURE-SLICED: H16[(slice*N_NODES + row)*16 + n16], slice = feature>>4.
// A-input: standard [row][128] for layer 0 (sliced=0), sliced fp32 for layers 1-2.
// 512 threads = 8 waves, 16 rows/wave -> 128 rows/block; split-bf16 MFMA (3 per acc).

__global__ __launch_bounds__(512, 4) void k_gemm_mfma(const float* __restrict__ X,
                                                      const short* __restrict__ fhi,
                                                      const short* __restrict__ flo,
                                                      const float* __restrict__ dinv,
                                                      __half* __restrict__ H16,
                                                      int sliced) {
    __shared__ short Bh[16384];    // 32 KB
    __shared__ short Bl[16384];    // 32 KB

    int t = threadIdx.x;
    int wave = t >> 6, lane = t & 63;
    int q = lane >> 4, n16 = lane & 15;
    int row_base = blockIdx.x * 128 + wave * 16;

    // hoist all A loads: 4 ks x 32 B per lane (in flight before any use)
    int r0 = row_base + n16;
    if (r0 > N_NODES - 1) r0 = N_NODES - 1;
    float4 a[4][2];
    if (!sliced) {
        const float* p0 = X + (long long)r0 * 128 + q * 8;
#pragma unroll
        for (int ks = 0; ks < 4; ++ks) {
            a[ks][0] = *(const float4*)(p0 + ks * 32);
            a[ks][1] = *(const float4*)(p0 + ks * 32 + 4);
        }
    } else {
        // feature chunk f0 = q*8 + ks*32 lives at slice f0>>4, offset f0&15
#pragma unroll
        for (int ks = 0; ks < 4; ++ks) {
            int sl = ks * 2 + (q >> 1);
            const float* p = X + ((long long)sl * N_NODES + r0) * 16 + (q & 1) * 8;
            a[ks][0] = *(const float4*)p;
            a[ks][1] = *(const float4*)(p + 4);
        }
    }

    // stage B frags into LDS: 2048 float4 per array, 512 threads -> 4 iters
    {
        const float4* sh_ = (const float4*)fhi;
        const float4* sl_ = (const float4*)flo;
        float4* dh = (float4*)Bh;
        float4* dl = (float4*)Bl;
#pragma unroll
        for (int i = 0; i < 4; ++i) {
            dh[t + i * 512] = sh_[t + i * 512];
            dl[t + i * 512] = sl_[t + i * 512];
        }
    }

    // split A into bf16 hi/lo fragments (under vmcnt shadow)
    sh8 ah[4], al[4];
#pragma unroll
    for (int ks = 0; ks < 4; ++ks) {
        float xs[8];
        xs[0] = a[ks][0].x; xs[1] = a[ks][0].y; xs[2] = a[ks][0].z; xs[3] = a[ks][0].w;
        xs[4] = a[ks][1].x; xs[5] = a[ks][1].y; xs[6] = a[ks][1].z; xs[7] = a[ks][1].w;
#pragma unroll
        for (int j = 0; j < 8; ++j) {
            short h, l;
            split_bf16(xs[j], h, l);
            ah[ks][j] = h;
            al[ks][j] = l;
        }
    }

    fl4 acc[8];
#pragma unroll
    for (int c = 0; c < 8; ++c) acc[c] = (fl4){0.f, 0.f, 0.f, 0.f};

    __syncthreads();

    // MFMA loop: pure LDS reads + MFMA (compiler pipelines via lgkmcnt)
#pragma unroll
    for (int ks = 0; ks < 4; ++ks)
#pragma unroll
        for (int c = 0; c < 8; ++c) {
            sh8 bh = *(const sh8*)&Bh[((ks * 8 + c) * 64 + lane) * 8];
            sh8 bl = *(const sh8*)&Bl[((ks * 8 + c) * 64 + lane) * 8];
            acc[c] = __builtin_amdgcn_mfma_f32_16x16x32_bf16(ah[ks], bh, acc[c], 0, 0, 0);
            acc[c] = __builtin_amdgcn_mfma_f32_16x16x32_bf16(al[ks], bh, acc[c], 0, 0, 0);
            acc[c] = __builtin_amdgcn_mfma_f32_16x16x32_bf16(ah[ks], bl, acc[c], 0, 0, 0);
        }

    // epilogue: C/D layout row = q*4 + reg, col = c*16 + n16 -> sliced H16
#pragma unroll
    for (int reg = 0; reg < 4; ++reg) {
        int grow = row_base + q * 4 + reg;
        if (grow < N_NODES) {
            float sc = dinv[grow];
#pragma unroll
            for (int c = 0; c < 8; ++c)
                H16[(c * N_NODES + grow) * 16 + n16] = __float2half(acc[c][reg] * sc);
        }
    }
}

// ---------------- gather aggregation + bias + relu (feature-sliced, LDS-staged) ----
// blockIdx % 8 = feature slice (pins slice to one XCD via round-robin dispatch);
// each XCD's 4 MB L2 holds its 3.2 MB H16 slice -> random src reads become L2 hits.
// Block stages its 32 nodes' contiguous csr range into LDS (wide nt loads, all in
// flight), then the edge loop runs UNCONDITIONAL clamped gathers -> deep pipelining.
// Per wave: 1 node at a time, 8 lanes/edge (4 B half2 each), 32 edges in flight.

__global__ __launch_bounds__(256) void k_gather(const __half2* __restrict__ H2,
                                                const int* __restrict__ csr_src,
                                                const int* __restrict__ row_ptr,
                                                const int* __restrict__ cnt,
                                                const float* __restrict__ dinv,
                                                const float* __restrict__ b,
                                                float* __restrict__ out,
                                                int std_out) {
    __shared__ int eidx[GCAP];

    int s = blockIdx.x & 7;                  // slice -> XCD (round-robin heuristic)
    int grp = blockIdx.x >> 3;               // node group: GNODES nodes per block
    int t = threadIdx.x;
    int wv = __builtin_amdgcn_readfirstlane(t >> 6);
    int lane = t & 63;
    int g8 = lane >> 3, f4 = lane & 7;       // edge subgroup / feature-pair
    int sbase = s * N_NODES;
    float2 bb = ((const float2*)b)[s * 8 + f4];

    int nbase = grp * GNODES;
    int e0 = row_ptr[nbase];
    int last = nbase + GNODES - 1;
    int eend = row_ptr[last] + cnt[last];
    int C = eend - e0;
    if (C > GCAP) C = GCAP;

    // cooperative stage: 4 nt loads in flight per thread per iteration
    for (int i0 = 0; i0 < C; i0 += 1024) {
        int v[4];
#pragma unroll
        for (int u = 0; u < 4; ++u) {
            int i = i0 + u * 256 + t;
            v[u] = (i < C) ? __builtin_nontemporal_load(csr_src + e0 + i) : 0;
        }
#pragma unroll
        for (int u = 0; u < 4; ++u) {
            int i = i0 + u * 256 + t;
            if (i < C) eidx[i] = v[u];
        }
    }
    __syncthreads();

    for (int k = 0; k < GNODES / 4; ++k) {   // 8 nodes per wave
        int node = nbase + wv * (GNODES / 4) + k;
        int start = row_ptr[node];
        int n = cnt[node];
        int lo = start - e0;

        float2 self_ = __half22float2(H2[(sbase + node) * 8 + f4]);
        float accx = (g8 == 0) ? self_.x : 0.0f;
        float accy = (g8 == 0) ? self_.y : 0.0f;

        if (n > 0) {
            int nm1 = n - 1;
            if (lo + n <= C) {
                // fast path: indices from LDS, unconditional clamped gathers
                for (int j = 0; j < n; j += 32) {
                    float2 h[4]; float m[4];
#pragma unroll
                    for (int u = 0; u < 4; ++u) {
                        int e = j + u * 8 + g8;
                        int ec = (e < nm1) ? e : nm1;
                        int idx = eidx[lo + ec];
                        h[u] = __half22float2(H2[(sbase + idx) * 8 + f4]);
                        m[u] = (e < n) ? 1.0f : 0.0f;
                    }
#pragma unroll
                    for (int u = 0; u < 4; ++u) {
                        accx = fmaf(h[u].x, m[u], accx);
                        accy = fmaf(h[u].y, m[u], accy);
                    }
                }
            } else {
                // rare fallback: indices straight from global (same structure)
                for (int j = 0; j < n; j += 32) {
                    float2 h[4]; float m[4];
#pragma unroll
                    for (int u = 0; u < 4; ++u) {
                        int e = j + u * 8 + g8;
                        int ec = (e < nm1) ? e : nm1;
                        int idx = __builtin_nontemporal_load(csr_src + start + ec);
                        h[u] = __half22float2(H2[(sbase + idx) * 8 + f4]);
                        m[u] = (e < n) ? 1.0f : 0.0f;
                    }
#pragma unroll
                    for (int u = 0; u < 4; ++u) {
                        accx = fmaf(h[u].x, m[u], accx);
                        accy = fmaf(h[u].y, m[u], accy);
                    }
                }
            }
        }

        // reduce across the 8 edge subgroups (lanes l, l^8, l^16, ..., l^56)
#pragma unroll
        for (int m2 = 8; m2 <= 32; m2 <<= 1) {
            accx += __shfl_xor(accx, m2, 64);
            accy += __shfl_xor(accy, m2, 64);
        }

        if (g8 == 0) {
            float dd = dinv[node];
            f2v v;
            v.x = fmaxf(fmaf(accx, dd, bb.x), 0.0f);
            v.y = fmaxf(fmaf(accy, dd, bb.y), 0.0f);
            if (std_out)
                __builtin_nontemporal_store(v, (f2v*)(out + node * 128 + s * 16) + f4);
            else
                __builtin_nontemporal_store(v, (f2v*)(out + (sbase + node) * 16) + f4);
        }
    }
}

// ---------------- launch ----------------

extern "C" void kernel_launch(void* const* d_in, const int* in_sizes, int n_in,
                              void* d_out, int out_size, void* d_ws, size_t ws_size,
                              hipStream_t stream) {
    const float* x  = (const float*)d_in[0];
    const int*   ei = (const int*)d_in[1];   // int32: [0,E)=src, [E,2E)=dst
    const float* Wm[3] = {(const float*)d_in[2], (const float*)d_in[4], (const float*)d_in[6]};
    const float* bv[3] = {(const float*)d_in[3], (const float*)d_in[5], (const float*)d_in[7]};
    float* out = (float*)d_out;

    char* w = (char*)d_ws;
    int*      row_ptr     = (int*)(w + 0);            // 0.4 MB
    int*      cnt         = (int*)(w + 400384);       // 0.4 MB
    float*    dinv        = (float*)(w + 800768);     // 0.4 MB
    int*      bucket_cnt  = (int*)(w + 1201152);      // 2 KB
    int*      bucket_base = (int*)(w + 1203200);      // 2 KB
    int*      bucket_fill = (int*)(w + 1205248);      // 2 KB
    unsigned* bpairs      = (unsigned*)(w + 1207296); // 12.8 MB
    int*      csr_src     = (int*)(w + 14007808);     // 12.8 MB
    short*    fragHi      = (short*)(w + 26808320);   // 96 KB (3 layers)
    short*    fragLo      = (short*)(w + 26906624);   // 96 KB
    __half*   H16         = (__half*)(w + 27004928);  // 25.6 MB sliced (total ~52.6 MB)

    // W repack (+ fused bucket zero), then bucketed counting-sort CSR build
    k_wprep<<<193, 256, 0, stream>>>(Wm[0], Wm[1], Wm[2], fragHi, fragLo, bucket_cnt);
    k_bhist<<<NCHUNKB, 256, 0, stream>>>(ei + N_EDGES, bucket_cnt);
    k_bscan<<<1, 512, 0, stream>>>(bucket_cnt, bucket_base, bucket_fill);
    k_bscatter<<<NCHUNKB, 256, 0, stream>>>(ei, bucket_fill, bpairs);
    k_bbuild<<<NBUCKETS, 256, 0, stream>>>(bpairs, bucket_base, row_ptr, cnt, dinv, csr_src);

    // 3 GCN layers; d_out doubles as the (sliced) fp32 ping buffer
    const float* xin = x;
    for (int l = 0; l < 3; ++l) {
        k_gemm_mfma<<<(N_NODES + 127) / 128, 512, 0, stream>>>(xin, fragHi + l * 16384,
                                                               fragLo + l * 16384, dinv, H16,
                                                               l > 0);
        k_gather<<<8 * (N_NODES / GNODES), 256, 0, stream>>>((const __half2*)H16, csr_src,
                                                             row_ptr, cnt, dinv, bv[l], out,
                                                             l == 2);
        xin = out;
    }
}

// Round 3
// 814.651 us; speedup vs baseline: 1.6077x; 1.2539x over previous
//
#include <hip/hip_runtime.h>
#include <hip/hip_fp16.h>

#define N_NODES 100000
#define N_EDGES 3200000
#define NBUCKETS 391          // ceil(100000 / 256); bucket = dst >> 8
#define NCHUNKB 256           // blocks for hist/scatter
#define CHUNK 12500           // N_EDGES / NCHUNKB
#define GNODES 32             // nodes per gather block
#define GCAP 2048             // LDS-staged edges per gather block (8 KB; mean load 1024)
// FEATURE == HIDDEN == 128
// edge_index arrives as int32: ei[0..E) = src, ei[E..2E) = dst.

typedef __attribute__((ext_vector_type(8))) short sh8;   // 8 bf16 (4 VGPRs)
typedef __attribute__((ext_vector_type(4))) float fl4;   // MFMA acc
typedef __attribute__((ext_vector_type(2))) float f2v;   // for nontemporal float2 store

// split fp32 into bf16 hi + bf16 lo (both round-to-nearest-even)
__device__ inline void split_bf16(float x, short& hi, short& lo) {
    unsigned u = __float_as_uint(x);
    unsigned r = u + 0x7FFFu + ((u >> 16) & 1u);
    hi = (short)(r >> 16);
    float hif = __uint_as_float(r & 0xFFFF0000u);
    float lof = x - hif;
    unsigned u2 = __float_as_uint(lof);
    lo = (short)((u2 + 0x7FFFu + ((u2 >> 16) & 1u)) >> 16);
}

// ---------------- bucketed CSR build ----------------

__global__ __launch_bounds__(256) void k_bhist(const int* __restrict__ ei_dst,
                                               int* __restrict__ bucket_cnt) {
    __shared__ int h[NBUCKETS];
    int t = threadIdx.x;
    for (int i = t; i < NBUCKETS; i += 256) h[i] = 0;
    __syncthreads();
    int base = blockIdx.x * CHUNK;
    for (int i = t; i < CHUNK; i += 256)
        atomicAdd(&h[ei_dst[base + i] >> 8], 1);
    __syncthreads();
    for (int i = t; i < NBUCKETS; i += 256)
        if (h[i]) atomicAdd(&bucket_cnt[i], h[i]);
}

__global__ __launch_bounds__(512) void k_bscan(const int* __restrict__ bucket_cnt,
                                               int* __restrict__ bucket_base,
                                               int* __restrict__ bucket_fill) {
    __shared__ int s[512];
    int t = threadIdx.x;
    int v = (t < NBUCKETS) ? bucket_cnt[t] : 0;
    s[t] = v;
    __syncthreads();
    for (int off = 1; off < 512; off <<= 1) {
        int x = (t >= off) ? s[t - off] : 0;
        __syncthreads();
        s[t] += x;
        __syncthreads();
    }
    int ex = s[t] - v;
    if (t < NBUCKETS) { bucket_base[t] = ex; bucket_fill[t] = ex; }
    if (t == NBUCKETS - 1) bucket_base[NBUCKETS] = s[t];
}

// packed entry: src (17 bits) | dstlocal (8 bits) << 17
__global__ __launch_bounds__(256) void k_bscatter(const int* __restrict__ ei,
                                                  int* __restrict__ bucket_fill,
                                                  unsigned* __restrict__ bpairs) {
    __shared__ int h[NBUCKETS];
    __shared__ int basep[NBUCKETS];
    int t = threadIdx.x;
    const int* dstp = ei + N_EDGES;
    int base = blockIdx.x * CHUNK;

    for (int i = t; i < NBUCKETS; i += 256) h[i] = 0;
    __syncthreads();
    for (int i = t; i < CHUNK; i += 256)
        atomicAdd(&h[dstp[base + i] >> 8], 1);
    __syncthreads();
    for (int i = t; i < NBUCKETS; i += 256) {
        int c = h[i];
        basep[i] = c ? atomicAdd(&bucket_fill[i], c) : 0;
    }
    __syncthreads();
    for (int i = t; i < NBUCKETS; i += 256) h[i] = 0;  // reuse as rank
    __syncthreads();
    for (int i = t; i < CHUNK; i += 256) {
        int d = dstp[base + i];
        int s = ei[base + i];
        int b = d >> 8;
        int r = atomicAdd(&h[b], 1);
        bpairs[basep[b] + r] = (unsigned)s | ((unsigned)(d & 255) << 17);
    }
}

__global__ __launch_bounds__(256) void k_bbuild(const unsigned* __restrict__ bpairs,
                                                const int* __restrict__ bucket_base,
                                                int* __restrict__ row_ptr,
                                                int* __restrict__ cnt,
                                                float* __restrict__ dinv,
                                                int* __restrict__ csr_src) {
    __shared__ int h[256];
    __shared__ int sc[256];
    int b = blockIdx.x;
    int t = threadIdx.x;
    int e0 = bucket_base[b], e1 = bucket_base[b + 1];

    h[t] = 0;
    __syncthreads();
    for (int i = e0 + t; i < e1; i += 256)
        atomicAdd(&h[bpairs[i] >> 17], 1);
    __syncthreads();
    int v = h[t];
    sc[t] = v;
    __syncthreads();
    for (int off = 1; off < 256; off <<= 1) {
        int x = (t >= off) ? sc[t - off] : 0;
        __syncthreads();
        sc[t] += x;
        __syncthreads();
    }
    int ex = sc[t] - v;
    int node = b * 256 + t;
    if (node < N_NODES) {
        cnt[node] = v;
        dinv[node] = rsqrtf((float)(v + 1));
        row_ptr[node] = e0 + ex;
    }
    __syncthreads();
    h[t] = e0 + ex;               // absolute fill cursor
    __syncthreads();
    for (int i = e0 + t; i < e1; i += 256) {
        unsigned p = bpairs[i];
        int pos = atomicAdd(&h[p >> 17], 1);
        csr_src[pos] = (int)(p & 0x1FFFFu);
    }
}

// ------- W repack (+ fused bucket_cnt zero in the extra block) -------
// B-frag (16x16x32): lane = q*16 + n16 holds B[k = ks*32 + q*8 + j][n = c*16 + n16],
// j = 0..7 contiguous. Storage: frag[((l*32 + ks*8 + c)*64 + lane)*8 + j].

__global__ __launch_bounds__(256) void k_wprep(const float* __restrict__ W0,
                                               const float* __restrict__ W1,
                                               const float* __restrict__ W2,
                                               short* __restrict__ fhi,
                                               short* __restrict__ flo,
                                               int* __restrict__ bucket_cnt) {
    if (blockIdx.x == 192) {   // fused: zero the bucket counters
        for (int i = threadIdx.x; i < NBUCKETS; i += 256) bucket_cnt[i] = 0;
        return;
    }
    int idx = blockIdx.x * 256 + threadIdx.x;   // 3 * 16384
    int l = idx >> 14, e = idx & 16383;
    const float* W = (l == 0) ? W0 : (l == 1) ? W1 : W2;
    float w = W[e];
    int k = e >> 7, n = e & 127;
    int ks = k >> 5, q = (k >> 3) & 3, j = k & 7;
    int c = n >> 4, n16 = n & 15;
    int lane = q * 16 + n16;
    int dst = ((l * 32 + ks * 8 + c) * 64 + lane) * 8 + j;
    short hi, lo;
    split_bf16(w, hi, lo);
    fhi[dst] = hi;
    flo[dst] = lo;
}

// ------- GEMM v5: H16 = fp16( (X @ W) * dinv[row] ), sliced output layout -------
// H16 is stored FEATURE-SLICED: H16[(slice*N_NODES + row)*16 + n16], slice = feature>>4.
// A-input: standard [row][128] for layer 0 (sliced=0), sliced fp32 for layers 1-2.
// 512 threads = 8 waves, 16 rows/wave -> 128 rows/block; split-bf16 MFMA (3 per acc).

__global__ __launch_bounds__(512, 4) void k_gemm_mfma(const float* __restrict__ X,
                                                      const short* __restrict__ fhi,
                                                      const short* __restrict__ flo,
                                                      const float* __restrict__ dinv,
                                                      __half* __restrict__ H16,
                                                      int sliced) {
    __shared__ short Bh[16384];    // 32 KB
    __shared__ short Bl[16384];    // 32 KB

    int t = threadIdx.x;
    int wave = t >> 6, lane = t & 63;
    int q = lane >> 4, n16 = lane & 15;
    int row_base = blockIdx.x * 128 + wave * 16;

    // hoist all A loads: 4 ks x 32 B per lane (in flight before any use)
    int r0 = row_base + n16;
    if (r0 > N_NODES - 1) r0 = N_NODES - 1;
    float4 a[4][2];
    if (!sliced) {
        const float* p0 = X + (long long)r0 * 128 + q * 8;
#pragma unroll
        for (int ks = 0; ks < 4; ++ks) {
            a[ks][0] = *(const float4*)(p0 + ks * 32);
            a[ks][1] = *(const float4*)(p0 + ks * 32 + 4);
        }
    } else {
        // feature chunk f0 = q*8 + ks*32 lives at slice f0>>4, offset f0&15
#pragma unroll
        for (int ks = 0; ks < 4; ++ks) {
            int sl = ks * 2 + (q >> 1);
            const float* p = X + ((long long)sl * N_NODES + r0) * 16 + (q & 1) * 8;
            a[ks][0] = *(const float4*)p;
            a[ks][1] = *(const float4*)(p + 4);
        }
    }

    // stage B frags into LDS: 2048 float4 per array, 512 threads -> 4 iters
    {
        const float4* sh_ = (const float4*)fhi;
        const float4* sl_ = (const float4*)flo;
        float4* dh = (float4*)Bh;
        float4* dl = (float4*)Bl;
#pragma unroll
        for (int i = 0; i < 4; ++i) {
            dh[t + i * 512] = sh_[t + i * 512];
            dl[t + i * 512] = sl_[t + i * 512];
        }
    }

    // split A into bf16 hi/lo fragments (under vmcnt shadow)
    sh8 ah[4], al[4];
#pragma unroll
    for (int ks = 0; ks < 4; ++ks) {
        float xs[8];
        xs[0] = a[ks][0].x; xs[1] = a[ks][0].y; xs[2] = a[ks][0].z; xs[3] = a[ks][0].w;
        xs[4] = a[ks][1].x; xs[5] = a[ks][1].y; xs[6] = a[ks][1].z; xs[7] = a[ks][1].w;
#pragma unroll
        for (int j = 0; j < 8; ++j) {
            short h, l;
            split_bf16(xs[j], h, l);
            ah[ks][j] = h;
            al[ks][j] = l;
        }
    }

    fl4 acc[8];
#pragma unroll
    for (int c = 0; c < 8; ++c) acc[c] = (fl4){0.f, 0.f, 0.f, 0.f};

    __syncthreads();

    // MFMA loop: pure LDS reads + MFMA (compiler pipelines via lgkmcnt)
#pragma unroll
    for (int ks = 0; ks < 4; ++ks)
#pragma unroll
        for (int c = 0; c < 8; ++c) {
            sh8 bh = *(const sh8*)&Bh[((ks * 8 + c) * 64 + lane) * 8];
            sh8 bl = *(const sh8*)&Bl[((ks * 8 + c) * 64 + lane) * 8];
            acc[c] = __builtin_amdgcn_mfma_f32_16x16x32_bf16(ah[ks], bh, acc[c], 0, 0, 0);
            acc[c] = __builtin_amdgcn_mfma_f32_16x16x32_bf16(al[ks], bh, acc[c], 0, 0, 0);
            acc[c] = __builtin_amdgcn_mfma_f32_16x16x32_bf16(ah[ks], bl, acc[c], 0, 0, 0);
        }

    // epilogue: C/D layout row = q*4 + reg, col = c*16 + n16 -> sliced H16
#pragma unroll
    for (int reg = 0; reg < 4; ++reg) {
        int grow = row_base + q * 4 + reg;
        if (grow < N_NODES) {
            float sc = dinv[grow];
#pragma unroll
            for (int c = 0; c < 8; ++c)
                H16[(c * N_NODES + grow) * 16 + n16] = __float2half(acc[c][reg] * sc);
        }
    }
}

// ---------------- gather aggregation + bias + relu (sliced, group-per-node) ----
// blockIdx % 8 = feature slice (pins slice to one XCD; 3.2 MB slice lives in its
// 4 MB L2). Wave = 8 groups x 8 lanes; each GROUP owns one node (8 nodes/wave in
// flight -> no cross-lane reduce, per-node overhead vectorized). Lane owns one
// feature-pair for the whole loop. Indices staged in LDS (8 KB -> full occupancy).
// Gathers are unconditional clamp+mask; saddr+32bit-offset addressing.

__global__ __launch_bounds__(256) void k_gather(const __half2* __restrict__ H2,
                                                const int* __restrict__ csr_src,
                                                const int* __restrict__ row_ptr,
                                                const int* __restrict__ cnt,
                                                const float* __restrict__ dinv,
                                                const float* __restrict__ b,
                                                float* __restrict__ out,
                                                int std_out) {
    __shared__ int eidx[GCAP];

    int s = blockIdx.x & 7;                  // slice -> XCD (round-robin heuristic)
    int grp = blockIdx.x >> 3;               // node group: GNODES nodes per block
    int t = threadIdx.x;
    int wv = t >> 6;
    int lane = t & 63;
    int g = lane >> 3, f4 = lane & 7;        // group (node) / feature-pair
    const __half2* Hs = H2 + (size_t)s * N_NODES * 8;   // uniform slice base
    float2 bb = ((const float2*)b)[s * 8 + f4];

    int nbase = grp * GNODES;
    int e0 = row_ptr[nbase];
    int last = nbase + GNODES - 1;
    int eend = row_ptr[last] + cnt[last];
    int C = eend - e0;
    if (C > GCAP) C = GCAP;

    // cooperative stage: up to 2048 edges, 8 nt loads in flight per thread
    {
        int v[8];
#pragma unroll
        for (int u = 0; u < 8; ++u) {
            int i = u * 256 + t;
            v[u] = (i < C) ? __builtin_nontemporal_load(csr_src + e0 + i) : 0;
        }
#pragma unroll
        for (int u = 0; u < 8; ++u) {
            int i = u * 256 + t;
            if (i < C) eidx[i] = v[u];
        }
    }
    __syncthreads();

    int node = nbase + wv * 8 + g;           // this group's node
    int start = row_ptr[node];
    int n = cnt[node];
    int lo = start - e0;

    // self contribution (H row already carries dinv[row])
    float2 self_ = __half22float2(Hs[(unsigned)(node * 8 + f4)]);
    float ax[4], ay[4];
    ax[0] = self_.x; ay[0] = self_.y;
    ax[1] = ax[2] = ax[3] = 0.0f;
    ay[1] = ay[2] = ay[3] = 0.0f;

    int nm1 = n - 1;
    if (n > 0) {
        if (lo + n <= C) {
            // fast path: indices from LDS, unconditional clamped gathers
            for (int j = 0; j < n; j += 8) {
                float2 h[8]; float m[8];
#pragma unroll
                for (int u = 0; u < 8; ++u) {
                    int e = j + u;
                    int ec = (e < nm1) ? e : nm1;
                    int idx = eidx[lo + ec];
                    h[u] = __half22float2(Hs[(unsigned)(idx * 8 + f4)]);
                    m[u] = (e < n) ? 1.0f : 0.0f;
                }
#pragma unroll
                for (int u = 0; u < 8; ++u) {
                    ax[u & 3] = fmaf(h[u].x, m[u], ax[u & 3]);
                    ay[u & 3] = fmaf(h[u].y, m[u], ay[u & 3]);
                }
            }
        } else {
            // rare fallback: indices straight from global (same structure)
            for (int j = 0; j < n; j += 8) {
                float2 h[8]; float m[8];
#pragma unroll
                for (int u = 0; u < 8; ++u) {
                    int e = j + u;
                    int ec = (e < nm1) ? e : nm1;
                    int idx = __builtin_nontemporal_load(csr_src + start + ec);
                    h[u] = __half22float2(Hs[(unsigned)(idx * 8 + f4)]);
                    m[u] = (e < n) ? 1.0f : 0.0f;
                }
#pragma unroll
                for (int u = 0; u < 8; ++u) {
                    ax[u & 3] = fmaf(h[u].x, m[u], ax[u & 3]);
                    ay[u & 3] = fmaf(h[u].y, m[u], ay[u & 3]);
                }
            }
        }
    }

    float accx = (ax[0] + ax[1]) + (ax[2] + ax[3]);
    float accy = (ay[0] + ay[1]) + (ay[2] + ay[3]);

    float dd = dinv[node];
    f2v v;
    v.x = fmaxf(fmaf(accx, dd, bb.x), 0.0f);
    v.y = fmaxf(fmaf(accy, dd, bb.y), 0.0f);
    if (std_out)
        __builtin_nontemporal_store(v, (f2v*)(out + (size_t)node * 128 + s * 16) + f4);
    else
        __builtin_nontemporal_store(v, (f2v*)(out + ((size_t)s * N_NODES + node) * 16) + f4);
}

// ---------------- launch ----------------

extern "C" void kernel_launch(void* const* d_in, const int* in_sizes, int n_in,
                              void* d_out, int out_size, void* d_ws, size_t ws_size,
                              hipStream_t stream) {
    const float* x  = (const float*)d_in[0];
    const int*   ei = (const int*)d_in[1];   // int32: [0,E)=src, [E,2E)=dst
    const float* Wm[3] = {(const float*)d_in[2], (const float*)d_in[4], (const float*)d_in[6]};
    const float* bv[3] = {(const float*)d_in[3], (const float*)d_in[5], (const float*)d_in[7]};
    float* out = (float*)d_out;

    char* w = (char*)d_ws;
    int*      row_ptr     = (int*)(w + 0);            // 0.4 MB
    int*      cnt         = (int*)(w + 400384);       // 0.4 MB
    float*    dinv        = (float*)(w + 800768);     // 0.4 MB
    int*      bucket_cnt  = (int*)(w + 1201152);      // 2 KB
    int*      bucket_base = (int*)(w + 1203200);      // 2 KB
    int*      bucket_fill = (int*)(w + 1205248);      // 2 KB
    unsigned* bpairs      = (unsigned*)(w + 1207296); // 12.8 MB
    int*      csr_src     = (int*)(w + 14007808);     // 12.8 MB
    short*    fragHi      = (short*)(w + 26808320);   // 96 KB (3 layers)
    short*    fragLo      = (short*)(w + 26906624);   // 96 KB
    __half*   H16         = (__half*)(w + 27004928);  // 25.6 MB sliced (total ~52.6 MB)

    // W repack (+ fused bucket zero), then bucketed counting-sort CSR build
    k_wprep<<<193, 256, 0, stream>>>(Wm[0], Wm[1], Wm[2], fragHi, fragLo, bucket_cnt);
    k_bhist<<<NCHUNKB, 256, 0, stream>>>(ei + N_EDGES, bucket_cnt);
    k_bscan<<<1, 512, 0, stream>>>(bucket_cnt, bucket_base, bucket_fill);
    k_bscatter<<<NCHUNKB, 256, 0, stream>>>(ei, bucket_fill, bpairs);
    k_bbuild<<<NBUCKETS, 256, 0, stream>>>(bpairs, bucket_base, row_ptr, cnt, dinv, csr_src);

    // 3 GCN layers; d_out doubles as the (sliced) fp32 ping buffer
    const float* xin = x;
    for (int l = 0; l < 3; ++l) {
        k_gemm_mfma<<<(N_NODES + 127) / 128, 512, 0, stream>>>(xin, fragHi + l * 16384,
                                                               fragLo + l * 16384, dinv, H16,
                                                               l > 0);
        k_gather<<<8 * (N_NODES / GNODES), 256, 0, stream>>>((const __half2*)H16, csr_src,
                                                             row_ptr, cnt, dinv, bv[l], out,
                                                             l == 2);
        xin = out;
    }
}